// Round 2
// baseline (247.289 us; speedup 1.0000x reference)
//
#include <hip/hip_runtime.h>
#include <hip/hip_bf16.h>
#include <stdint.h>

// Problem constants (fixed by reference)
#define NB    8
#define NS    2048
#define NE    1024
#define NH    16
#define NDK   64
#define MTOK  (NB*NS)      // 16384 tokens

typedef __attribute__((ext_vector_type(8))) short bf16x8;
typedef __attribute__((ext_vector_type(4))) float f32x4;

// round-to-nearest-even f32 -> bf16 bits
__device__ __forceinline__ ushort f2bf(float f) {
  uint32_t u = __float_as_uint(f);
  u += 0x7FFFu + ((u >> 16) & 1u);
  return (ushort)(u >> 16);
}
__device__ __forceinline__ float bf2f(short s) {
  return __uint_as_float(((uint32_t)(ushort)s) << 16);
}

__device__ __forceinline__ void gload16(const void* g, void* l) {
  __builtin_amdgcn_global_load_lds(
      (const __attribute__((address_space(1))) void*)g,
      (__attribute__((address_space(3))) void*)l, 16, 0, 0);
}

// ---------------- f32 -> bf16 cast (vectorized) ----------------
__global__ __launch_bounds__(256) void cvt_bf16(const float* __restrict__ in,
                                                ushort* __restrict__ out, int n4) {
  int stride = gridDim.x * blockDim.x;
  for (int j = blockIdx.x * blockDim.x + threadIdx.x; j < n4; j += stride) {
    float4 v = ((const float4*)in)[j];
    ushort4 o;
    o.x = f2bf(v.x); o.y = f2bf(v.y); o.z = f2bf(v.z); o.w = f2bf(v.w);
    ((ushort4*)out)[j] = o;
  }
}

// ---------------- bf16 GEMM: C[m,n] = sum_k A[m,k]*B[n,k] ----------------
// 128x128 tile, BK=32, 4 waves (2x2), 4x4 16x16x32 fragments per wave.
#define BM 128
#define BN 128
#define BK 32

// f32-output variant (GEMM2)
__global__ __launch_bounds__(256) void gemm_bt(const ushort* __restrict__ A,
                                               const ushort* __restrict__ Bm,
                                               float* __restrict__ C,
                                               int M, int N, int K) {
  __shared__ ushort As[2][BM * BK];
  __shared__ ushort Bs[2][BN * BK];

  int tid  = threadIdx.x;
  int lane = tid & 63;
  int w    = tid >> 6;
  int wr   = w >> 1, wc = w & 1;
  int bc   = blockIdx.x, br = blockIdx.y;

  const ushort* Abase = A  + (size_t)(br * BM) * K;
  const ushort* Bbase = Bm + (size_t)(bc * BN) * K;

  int srow = lane >> 2;        // 0..15 rows within a 1KB chunk
  int skk  = (lane & 3) * 8;   // k-offset elems

  f32x4 zero = {0.f, 0.f, 0.f, 0.f};
  f32x4 acc[4][4];
#pragma unroll
  for (int m = 0; m < 4; ++m)
#pragma unroll
    for (int n = 0; n < 4; ++n) acc[m][n] = zero;

  int NKT = K / BK;
  int cur = 0;

#pragma unroll
  for (int j = 0; j < 2; ++j) {
    int c = w * 2 + j;
    gload16(Abase + (size_t)(c * 16 + srow) * K + skk, &As[0][c * 512]);
    gload16(Bbase + (size_t)(c * 16 + srow) * K + skk, &Bs[0][c * 512]);
  }

  int fr = lane & 15;
  int fk = (lane >> 4) * 8;

  for (int kt = 0; kt < NKT; ++kt) {
    __syncthreads();
    if (kt + 1 < NKT) {
      int k0 = (kt + 1) * BK;
#pragma unroll
      for (int j = 0; j < 2; ++j) {
        int c = w * 2 + j;
        gload16(Abase + (size_t)(c * 16 + srow) * K + k0 + skk, &As[cur ^ 1][c * 512]);
        gload16(Bbase + (size_t)(c * 16 + srow) * K + k0 + skk, &Bs[cur ^ 1][c * 512]);
      }
    }
    bf16x8 af[4], bfr[4];
#pragma unroll
    for (int m = 0; m < 4; ++m)
      af[m] = *(const bf16x8*)&As[cur][(wr * 64 + m * 16 + fr) * BK + fk];
#pragma unroll
    for (int n = 0; n < 4; ++n)
      bfr[n] = *(const bf16x8*)&Bs[cur][(wc * 64 + n * 16 + fr) * BK + fk];
#pragma unroll
    for (int m = 0; m < 4; ++m)
#pragma unroll
      for (int n = 0; n < 4; ++n)
        acc[m][n] = __builtin_amdgcn_mfma_f32_16x16x32_bf16(af[m], bfr[n], acc[m][n], 0, 0, 0);
    cur ^= 1;
  }

  int row0 = br * BM + wr * 64 + (lane >> 4) * 4;
  int col0 = bc * BN + wc * 64 + (lane & 15);
#pragma unroll
  for (int m = 0; m < 4; ++m)
#pragma unroll
    for (int n = 0; n < 4; ++n)
#pragma unroll
      for (int i = 0; i < 4; ++i)
        C[(size_t)(row0 + m * 16 + i) * N + col0 + n * 16] = acc[m][n][i];
}

// bf16-output variant with fused quantum projection epilogue (GEMM1):
// qq[m,n] = cos(theta[n&63]) * cos(proj[m,n]), stored bf16.
__global__ __launch_bounds__(256) void gemm_bt_cos(const ushort* __restrict__ A,
                                                   const ushort* __restrict__ Bm,
                                                   ushort* __restrict__ Cq,
                                                   const float* __restrict__ theta,
                                                   int M, int N, int K) {
  __shared__ ushort As[2][BM * BK];
  __shared__ ushort Bs[2][BN * BK];

  int tid  = threadIdx.x;
  int lane = tid & 63;
  int w    = tid >> 6;
  int wr   = w >> 1, wc = w & 1;
  int bc   = blockIdx.x, br = blockIdx.y;

  const ushort* Abase = A  + (size_t)(br * BM) * K;
  const ushort* Bbase = Bm + (size_t)(bc * BN) * K;

  int srow = lane >> 2;
  int skk  = (lane & 3) * 8;

  f32x4 zero = {0.f, 0.f, 0.f, 0.f};
  f32x4 acc[4][4];
#pragma unroll
  for (int m = 0; m < 4; ++m)
#pragma unroll
    for (int n = 0; n < 4; ++n) acc[m][n] = zero;

  int NKT = K / BK;
  int cur = 0;

#pragma unroll
  for (int j = 0; j < 2; ++j) {
    int c = w * 2 + j;
    gload16(Abase + (size_t)(c * 16 + srow) * K + skk, &As[0][c * 512]);
    gload16(Bbase + (size_t)(c * 16 + srow) * K + skk, &Bs[0][c * 512]);
  }

  int fr = lane & 15;
  int fk = (lane >> 4) * 8;

  for (int kt = 0; kt < NKT; ++kt) {
    __syncthreads();
    if (kt + 1 < NKT) {
      int k0 = (kt + 1) * BK;
#pragma unroll
      for (int j = 0; j < 2; ++j) {
        int c = w * 2 + j;
        gload16(Abase + (size_t)(c * 16 + srow) * K + k0 + skk, &As[cur ^ 1][c * 512]);
        gload16(Bbase + (size_t)(c * 16 + srow) * K + k0 + skk, &Bs[cur ^ 1][c * 512]);
      }
    }
    bf16x8 af[4], bfr[4];
#pragma unroll
    for (int m = 0; m < 4; ++m)
      af[m] = *(const bf16x8*)&As[cur][(wr * 64 + m * 16 + fr) * BK + fk];
#pragma unroll
    for (int n = 0; n < 4; ++n)
      bfr[n] = *(const bf16x8*)&Bs[cur][(wc * 64 + n * 16 + fr) * BK + fk];
#pragma unroll
    for (int m = 0; m < 4; ++m)
#pragma unroll
      for (int n = 0; n < 4; ++n)
        acc[m][n] = __builtin_amdgcn_mfma_f32_16x16x32_bf16(af[m], bfr[n], acc[m][n], 0, 0, 0);
    cur ^= 1;
  }

  // theta index for col = bc*128 + wc*64 + n*16 + fr is (n*16+fr) & 63 = n*16+fr
  float ct[4];
#pragma unroll
  for (int n = 0; n < 4; ++n) ct[n] = __cosf(theta[n * 16 + fr]);

  int row0 = br * BM + wr * 64 + (lane >> 4) * 4;
  int col0 = bc * BN + wc * 64 + fr;
#pragma unroll
  for (int m = 0; m < 4; ++m)
#pragma unroll
    for (int n = 0; n < 4; ++n)
#pragma unroll
      for (int i = 0; i < 4; ++i)
        Cq[(size_t)(row0 + m * 16 + i) * N + col0 + n * 16] =
            f2bf(ct[n] * __cosf(acc[m][n][i]));
}

// ---------------- per-token head-vs-head attention ----------------
// 1 wave per token, 4 tokens per block (256 threads). qq (bf16 in, f32 in LDS).
// lane -> (h = lane>>2, qd = lane&3); lane owns dims d = qd*16..qd*16+15 of head h.
// LDS layout: token stride 1064 floats (mod 32 = 8), head stride 66 (mod 32 = 2).
#define TOKSTR 1064
#define HSTR   66

__global__ __launch_bounds__(256) void attn_quantum(const ushort* __restrict__ qqb,
                                                    ushort* __restrict__ aout) {
  __shared__ float qq[4 * TOKSTR];
  int tid = threadIdx.x;
  int t   = tid >> 6;    // token within block (= wave id)
  int l   = tid & 63;
  size_t tok = (size_t)blockIdx.x * 4 + t;
  const ushort* src = qqb + tok * NE;
  float* q = qq + t * TOKSTR;

  // phase 1: load 1024 bf16 -> f32 LDS (each lane 2x ushort8 = 16 floats)
#pragma unroll
  for (int c = 0; c < 2; ++c) {
    bf16x8 v = *(const bf16x8*)(src + c * 512 + l * 8);
    int p = c * 512 + l * 8;            // flat position, d = p&63 in [0,56]
    int base = (p >> 6) * HSTR + (p & 63);
    float4 f0, f1;
    f0.x = bf2f(v[0]); f0.y = bf2f(v[1]); f0.z = bf2f(v[2]); f0.w = bf2f(v[3]);
    f1.x = bf2f(v[4]); f1.y = bf2f(v[5]); f1.z = bf2f(v[6]); f1.w = bf2f(v[7]);
    *(float4*)&q[base]     = f0;
    *(float4*)&q[base + 4] = f1;
  }
  __syncthreads();

  int h  = l >> 2;
  int qd = l & 3;
  int d0 = qd * 16;

  // own-head slice
  float myq[16];
#pragma unroll
  for (int i = 0; i < 4; ++i)
    *(float4*)&myq[i * 4] = *(const float4*)&q[h * HSTR + d0 + i * 4];

  // phase 2: partial scores over my 16 dims, all 16 g
  float s[NH];
#pragma unroll
  for (int g = 0; g < NH; ++g) {
    float acc = 0.f;
#pragma unroll
    for (int i = 0; i < 4; ++i) {
      float4 r = *(const float4*)&q[g * HSTR + d0 + i * 4];
      acc += myq[i * 4 + 0] * r.x + myq[i * 4 + 1] * r.y +
             myq[i * 4 + 2] * r.z + myq[i * 4 + 3] * r.w;
    }
    s[g] = acc;
  }
  // reduce across the 4 qd lanes (lane bits 0,1)
#pragma unroll
  for (int g = 0; g < NH; ++g) {
    s[g] += __shfl_xor(s[g], 1);
    s[g] += __shfl_xor(s[g], 2);
    s[g] *= 0.125f;   // 1/sqrt(64)
  }

  // softmax over g (redundant in the 4 qd lanes, identical result)
  float mx = s[0];
#pragma unroll
  for (int g = 1; g < NH; ++g) mx = fmaxf(mx, s[g]);
  float sum = 0.f;
#pragma unroll
  for (int g = 0; g < NH; ++g) { s[g] = __expf(s[g] - mx); sum += s[g]; }
  float inv = 1.f / sum;

  // phase 3: out[h, d0+i] = sum_g attn[g] * qq[g][d0+i]
  float o[16];
#pragma unroll
  for (int i = 0; i < 16; ++i) o[i] = 0.f;
#pragma unroll
  for (int g = 0; g < NH; ++g) {
    float a = s[g] * inv;
#pragma unroll
    for (int i = 0; i < 4; ++i) {
      float4 r = *(const float4*)&q[g * HSTR + d0 + i * 4];
      o[i * 4 + 0] += a * r.x; o[i * 4 + 1] += a * r.y;
      o[i * 4 + 2] += a * r.z; o[i * 4 + 3] += a * r.w;
    }
  }

  // write 16 bf16, contiguous per lane (lane*32B): fully coalesced
  bf16x8 p0, p1;
#pragma unroll
  for (int j = 0; j < 8; ++j) { p0[j] = (short)f2bf(o[j]); p1[j] = (short)f2bf(o[8 + j]); }
  ushort* dst = aout + tok * NE + h * NDK + d0;
  *(bf16x8*)dst       = p0;
  *(bf16x8*)(dst + 8) = p1;
}

// ---------------- launch ----------------
extern "C" void kernel_launch(void* const* d_in, const int* in_sizes, int n_in,
                              void* d_out, int out_size, void* d_ws, size_t ws_size,
                              hipStream_t stream) {
  const float* x     = (const float*)d_in[0];
  const float* W     = (const float*)d_in[1];
  const float* theta = (const float*)d_in[2];
  float* out = (float*)d_out;

  char* ws = (char*)d_ws;
  ushort* xb  = (ushort*)ws;                                   // 32 MB
  ushort* Wb  = (ushort*)(ws + (size_t)MTOK * NE * 2);         // 2 MB
  ushort* qqb = (ushort*)(ws + (size_t)MTOK * NE * 2 + (size_t)NE * NE * 2); // 32 MB
  ushort* aout = xb;  // reuse: xb dead after GEMM1

  cvt_bf16<<<1024, 256, 0, stream>>>(x, xb, MTOK * NE / 4);
  cvt_bf16<<<256, 256, 0, stream>>>(W, Wb, NE * NE / 4);

  dim3 gg(NE / BN, MTOK / BM);  // (8, 128)
  gemm_bt_cos<<<gg, 256, 0, stream>>>(xb, Wb, qqb, theta, MTOK, NE, NE);

  attn_quantum<<<MTOK / 4, 256, 0, stream>>>(qqb, aout);

  gemm_bt<<<gg, 256, 0, stream>>>(aout, Wb, out, MTOK, NE, NE);
}

// Round 3
// 148.734 us; speedup vs baseline: 1.6626x; 1.6626x over previous
//
#include <hip/hip_runtime.h>
#include <hip/hip_bf16.h>
#include <stdint.h>

// Problem constants (fixed by reference)
#define NB    8
#define NS    2048
#define NE    1024
#define NH    16
#define NDK   64
#define MTOK  (NB*NS)      // 16384 tokens

typedef __attribute__((ext_vector_type(8))) short bf16x8;
typedef __attribute__((ext_vector_type(4))) float f32x4;

// round-to-nearest-even f32 -> bf16 bits
__device__ __forceinline__ ushort f2bf(float f) {
  uint32_t u = __float_as_uint(f);
  u += 0x7FFFu + ((u >> 16) & 1u);
  return (ushort)(u >> 16);
}

__device__ __forceinline__ void gload16(const void* g, void* l) {
  __builtin_amdgcn_global_load_lds(
      (const __attribute__((address_space(1))) void*)g,
      (__attribute__((address_space(3))) void*)l, 16, 0, 0);
}

// ---------------- f32 -> bf16 cast (vectorized) ----------------
__global__ __launch_bounds__(256) void cvt_bf16(const float* __restrict__ in,
                                                ushort* __restrict__ out, int n4) {
  int stride = gridDim.x * blockDim.x;
  for (int j = blockIdx.x * blockDim.x + threadIdx.x; j < n4; j += stride) {
    float4 v = ((const float4*)in)[j];
    ushort4 o;
    o.x = f2bf(v.x); o.y = f2bf(v.y); o.z = f2bf(v.z); o.w = f2bf(v.w);
    ((ushort4*)out)[j] = o;
  }
}

// ---------------- bf16 GEMM: C[m,n] = sum_k A[m,k]*B[n,k] ----------------
#define BM 128
#define BN 128
#define BK 32

// f32-output variant (GEMM2)
__global__ __launch_bounds__(256) void gemm_bt(const ushort* __restrict__ A,
                                               const ushort* __restrict__ Bm,
                                               float* __restrict__ C,
                                               int M, int N, int K) {
  __shared__ ushort As[2][BM * BK];
  __shared__ ushort Bs[2][BN * BK];

  int tid  = threadIdx.x;
  int lane = tid & 63;
  int w    = tid >> 6;
  int wr   = w >> 1, wc = w & 1;
  int bc   = blockIdx.x, br = blockIdx.y;

  const ushort* Abase = A  + (size_t)(br * BM) * K;
  const ushort* Bbase = Bm + (size_t)(bc * BN) * K;

  int srow = lane >> 2;
  int skk  = (lane & 3) * 8;

  f32x4 zero = {0.f, 0.f, 0.f, 0.f};
  f32x4 acc[4][4];
#pragma unroll
  for (int m = 0; m < 4; ++m)
#pragma unroll
    for (int n = 0; n < 4; ++n) acc[m][n] = zero;

  int NKT = K / BK;
  int cur = 0;

#pragma unroll
  for (int j = 0; j < 2; ++j) {
    int c = w * 2 + j;
    gload16(Abase + (size_t)(c * 16 + srow) * K + skk, &As[0][c * 512]);
    gload16(Bbase + (size_t)(c * 16 + srow) * K + skk, &Bs[0][c * 512]);
  }

  int fr = lane & 15;
  int fk = (lane >> 4) * 8;

  for (int kt = 0; kt < NKT; ++kt) {
    __syncthreads();
    if (kt + 1 < NKT) {
      int k0 = (kt + 1) * BK;
#pragma unroll
      for (int j = 0; j < 2; ++j) {
        int c = w * 2 + j;
        gload16(Abase + (size_t)(c * 16 + srow) * K + k0 + skk, &As[cur ^ 1][c * 512]);
        gload16(Bbase + (size_t)(c * 16 + srow) * K + k0 + skk, &Bs[cur ^ 1][c * 512]);
      }
    }
    bf16x8 af[4], bfr[4];
#pragma unroll
    for (int m = 0; m < 4; ++m)
      af[m] = *(const bf16x8*)&As[cur][(wr * 64 + m * 16 + fr) * BK + fk];
#pragma unroll
    for (int n = 0; n < 4; ++n)
      bfr[n] = *(const bf16x8*)&Bs[cur][(wc * 64 + n * 16 + fr) * BK + fk];
#pragma unroll
    for (int m = 0; m < 4; ++m)
#pragma unroll
      for (int n = 0; n < 4; ++n)
        acc[m][n] = __builtin_amdgcn_mfma_f32_16x16x32_bf16(af[m], bfr[n], acc[m][n], 0, 0, 0);
    cur ^= 1;
  }

  int row0 = br * BM + wr * 64 + (lane >> 4) * 4;
  int col0 = bc * BN + wc * 64 + (lane & 15);
#pragma unroll
  for (int m = 0; m < 4; ++m)
#pragma unroll
    for (int n = 0; n < 4; ++n)
#pragma unroll
      for (int i = 0; i < 4; ++i)
        C[(size_t)(row0 + m * 16 + i) * N + col0 + n * 16] = acc[m][n][i];
}

// bf16-output variant with fused quantum projection epilogue (GEMM1):
// qq[m,n] = cos(theta[n&63]) * cos(proj[m,n]), stored bf16.
__global__ __launch_bounds__(256) void gemm_bt_cos(const ushort* __restrict__ A,
                                                   const ushort* __restrict__ Bm,
                                                   ushort* __restrict__ Cq,
                                                   const float* __restrict__ theta,
                                                   int M, int N, int K) {
  __shared__ ushort As[2][BM * BK];
  __shared__ ushort Bs[2][BN * BK];

  int tid  = threadIdx.x;
  int lane = tid & 63;
  int w    = tid >> 6;
  int wr   = w >> 1, wc = w & 1;
  int bc   = blockIdx.x, br = blockIdx.y;

  const ushort* Abase = A  + (size_t)(br * BM) * K;
  const ushort* Bbase = Bm + (size_t)(bc * BN) * K;

  int srow = lane >> 2;
  int skk  = (lane & 3) * 8;

  f32x4 zero = {0.f, 0.f, 0.f, 0.f};
  f32x4 acc[4][4];
#pragma unroll
  for (int m = 0; m < 4; ++m)
#pragma unroll
    for (int n = 0; n < 4; ++n) acc[m][n] = zero;

  int NKT = K / BK;
  int cur = 0;

#pragma unroll
  for (int j = 0; j < 2; ++j) {
    int c = w * 2 + j;
    gload16(Abase + (size_t)(c * 16 + srow) * K + skk, &As[0][c * 512]);
    gload16(Bbase + (size_t)(c * 16 + srow) * K + skk, &Bs[0][c * 512]);
  }

  int fr = lane & 15;
  int fk = (lane >> 4) * 8;

  for (int kt = 0; kt < NKT; ++kt) {
    __syncthreads();
    if (kt + 1 < NKT) {
      int k0 = (kt + 1) * BK;
#pragma unroll
      for (int j = 0; j < 2; ++j) {
        int c = w * 2 + j;
        gload16(Abase + (size_t)(c * 16 + srow) * K + k0 + skk, &As[cur ^ 1][c * 512]);
        gload16(Bbase + (size_t)(c * 16 + srow) * K + k0 + skk, &Bs[cur ^ 1][c * 512]);
      }
    }
    bf16x8 af[4], bfr[4];
#pragma unroll
    for (int m = 0; m < 4; ++m)
      af[m] = *(const bf16x8*)&As[cur][(wr * 64 + m * 16 + fr) * BK + fk];
#pragma unroll
    for (int n = 0; n < 4; ++n)
      bfr[n] = *(const bf16x8*)&Bs[cur][(wc * 64 + n * 16 + fr) * BK + fk];
#pragma unroll
    for (int m = 0; m < 4; ++m)
#pragma unroll
      for (int n = 0; n < 4; ++n)
        acc[m][n] = __builtin_amdgcn_mfma_f32_16x16x32_bf16(af[m], bfr[n], acc[m][n], 0, 0, 0);
    cur ^= 1;
  }

  float ct[4];
#pragma unroll
  for (int n = 0; n < 4; ++n) ct[n] = __cosf(theta[n * 16 + fr]);

  int row0 = br * BM + wr * 64 + (lane >> 4) * 4;
  int col0 = bc * BN + wc * 64 + fr;
#pragma unroll
  for (int m = 0; m < 4; ++m)
#pragma unroll
    for (int n = 0; n < 4; ++n)
#pragma unroll
      for (int i = 0; i < 4; ++i)
        Cq[(size_t)(row0 + m * 16 + i) * N + col0 + n * 16] =
            f2bf(ct[n] * __cosf(acc[m][n][i]));
}

// ---------------- per-token head-vs-head attention via MFMA ----------------
// 1 wave = 1 token. H[d][g] = qq[g*64+d] (g=head, d=wire).
// Scores: S = H^T H via self-product MFMA (frag serves as A and B).
// Softmax per column h (cross lane-group shfl reduce).
// PV: O^T[h][d] = sum_g P^T[h][g] * H^T[g][d]; A-frag = regrouped P (K padded
// to 32, lanes kb>=2 zeroed), B-frag = LDS-transposed H (swizzled, b128 reads).
__global__ __launch_bounds__(256) void attn_quantum(const ushort* __restrict__ qqb,
                                                    ushort* __restrict__ aout) {
  // per-wave transpose buffer: 64 rows (d) x 32 cols, 8-ushort slot swizzle:
  // T[d][g] at d*32 + ((g>>3) ^ ((d>>3)&3))*8 + (g&7)   (only g<16 written/read)
  __shared__ ushort T[4][64 * 32];
  int tid = threadIdx.x;
  int wv  = tid >> 6, l = tid & 63;
  size_t tok = (size_t)blockIdx.x * 4 + wv;
  const ushort* src = qqb + tok * NE;
  ushort* Tw = T[wv];

  int h  = l & 15;   // head / fragment row-col index
  int kb = l >> 4;   // k-block 0..3

  // own fragment: qq[h*64 + kb*8 + jj] (d = kb*8+jj) and +32
  bf16x8 f0 = *(const bf16x8*)(src + h * 64 + kb * 8);
  bf16x8 f1 = *(const bf16x8*)(src + h * 64 + kb * 8 + 32);

  // transpose into LDS (swizzled): T[d][h] = H[d][h]
#pragma unroll
  for (int jj = 0; jj < 8; ++jj) {
    int d0 = kb * 8 + jj;
    int d1 = d0 + 32;
    Tw[d0 * 32 + (((h >> 3) ^ ((d0 >> 3) & 3)) << 3) + (h & 7)] = (ushort)f0[jj];
    Tw[d1 * 32 + (((h >> 3) ^ ((d1 >> 3) & 3)) << 3) + (h & 7)] = (ushort)f1[jj];
  }

  // scores: S[i][j] = sum_d qq[i*64+d]*qq[j*64+d]; frag is both A and B
  f32x4 sa = {0.f, 0.f, 0.f, 0.f};
  sa = __builtin_amdgcn_mfma_f32_16x16x32_bf16(f0, f0, sa, 0, 0, 0);
  sa = __builtin_amdgcn_mfma_f32_16x16x32_bf16(f1, f1, sa, 0, 0, 0);
  // lane holds S[g][h] for h = l&15 (col), g = kb*4+i (row)

  float s[4];
#pragma unroll
  for (int i = 0; i < 4; ++i) s[i] = sa[i] * 0.125f;   // 1/sqrt(64)

  // softmax over g (per column h): reduce across lane-groups (xor 16, 32)
  float mx = fmaxf(fmaxf(s[0], s[1]), fmaxf(s[2], s[3]));
  mx = fmaxf(mx, __shfl_xor(mx, 16));
  mx = fmaxf(mx, __shfl_xor(mx, 32));
  float e[4], sum = 0.f;
#pragma unroll
  for (int i = 0; i < 4; ++i) { e[i] = __expf(s[i] - mx); sum += e[i]; }
  sum += __shfl_xor(sum, 16);
  sum += __shfl_xor(sum, 32);
  float inv = 1.f / sum;
#pragma unroll
  for (int i = 0; i < 4; ++i) e[i] *= inv;   // P[g][h], normalized

  // regroup P into PV A-frag: lane (h,kb) needs P[kb*8+jj][h], jj=0..7
  // sources: lane h+(kb&1)*32 (jj=0..3) and +16 (jj=4..7); kb>=2 -> zero pad
  int s1 = h + (kb & 1) * 32;
  float q1[4], q2[4];
#pragma unroll
  for (int i = 0; i < 4; ++i) {
    q1[i] = __shfl(e[i], s1);
    q2[i] = __shfl(e[i], s1 + 16);
  }
  bool live = (kb < 2);
  bf16x8 pa;
#pragma unroll
  for (int i = 0; i < 4; ++i) {
    pa[i]     = live ? (short)f2bf(q1[i]) : (short)0;
    pa[4 + i] = live ? (short)f2bf(q2[i]) : (short)0;
  }

  __syncthreads();  // LDS transpose visible (also orders ds_write before ds_read)

  // PV: 4 chunks of 16 d-cols. B-frag: T rows c*16+(l&15), g-granule kb&1
  f32x4 o[4];
#pragma unroll
  for (int c = 0; c < 4; ++c) {
    int r = c * 16 + h;
    int slot = (kb & 1) ^ ((r >> 3) & 3);
    bf16x8 bfrag = *(const bf16x8*)&Tw[r * 32 + slot * 8];
    f32x4 z = {0.f, 0.f, 0.f, 0.f};
    o[c] = __builtin_amdgcn_mfma_f32_16x16x32_bf16(pa, bfrag, z, 0, 0, 0);
  }

  // lane holds O^T[h_out = kb*4+i][d = c*16 + (l&15)]
  ushort* dst = aout + tok * NE;
#pragma unroll
  for (int c = 0; c < 4; ++c)
#pragma unroll
    for (int i = 0; i < 4; ++i)
      dst[(kb * 4 + i) * NDK + c * 16 + h] = f2bf(o[c][i]);
}

// ---------------- launch ----------------
extern "C" void kernel_launch(void* const* d_in, const int* in_sizes, int n_in,
                              void* d_out, int out_size, void* d_ws, size_t ws_size,
                              hipStream_t stream) {
  const float* x     = (const float*)d_in[0];
  const float* W     = (const float*)d_in[1];
  const float* theta = (const float*)d_in[2];
  float* out = (float*)d_out;

  char* ws = (char*)d_ws;
  ushort* xb  = (ushort*)ws;                                   // 32 MB
  ushort* Wb  = (ushort*)(ws + (size_t)MTOK * NE * 2);         // 2 MB
  ushort* qqb = (ushort*)(ws + (size_t)MTOK * NE * 2 + (size_t)NE * NE * 2); // 32 MB
  ushort* aout = xb;  // reuse: xb dead after GEMM1

  cvt_bf16<<<1024, 256, 0, stream>>>(x, xb, MTOK * NE / 4);
  cvt_bf16<<<256, 256, 0, stream>>>(W, Wb, NE * NE / 4);

  dim3 gg(NE / BN, MTOK / BM);  // (8, 128)
  gemm_bt_cos<<<gg, 256, 0, stream>>>(xb, Wb, qqb, theta, MTOK, NE, NE);

  attn_quantum<<<MTOK / 4, 256, 0, stream>>>(qqb, aout);

  gemm_bt<<<gg, 256, 0, stream>>>(aout, Wb, out, MTOK, NE, NE);
}

// Round 4
// 128.547 us; speedup vs baseline: 1.9237x; 1.1570x over previous
//
#include <hip/hip_runtime.h>
#include <hip/hip_bf16.h>
#include <stdint.h>

// Problem constants (fixed by reference)
#define NB    8
#define NS    2048
#define NE    1024
#define NH    16
#define NDK   64
#define MTOK  (NB*NS)      // 16384 tokens

typedef __attribute__((ext_vector_type(8))) short bf16x8;
typedef __attribute__((ext_vector_type(4))) float f32x4;

// round-to-nearest-even f32 -> bf16 bits
__device__ __forceinline__ ushort f2bf(float f) {
  uint32_t u = __float_as_uint(f);
  u += 0x7FFFu + ((u >> 16) & 1u);
  return (ushort)(u >> 16);
}

__device__ __forceinline__ void gload16(const void* g, void* l) {
  __builtin_amdgcn_global_load_lds(
      (const __attribute__((address_space(1))) void*)g,
      (__attribute__((address_space(3))) void*)l, 16, 0, 0);
}

// ---------------- f32 -> bf16 cast (vectorized) ----------------
__global__ __launch_bounds__(256) void cvt_bf16(const float* __restrict__ in,
                                                ushort* __restrict__ out, int n4) {
  int stride = gridDim.x * blockDim.x;
  for (int j = blockIdx.x * blockDim.x + threadIdx.x; j < n4; j += stride) {
    float4 v = ((const float4*)in)[j];
    ushort4 o;
    o.x = f2bf(v.x); o.y = f2bf(v.y); o.z = f2bf(v.z); o.w = f2bf(v.w);
    ((ushort4*)out)[j] = o;
  }
}

// ---------------- bf16 GEMM: C[m,n] = sum_k A[m,k]*B[n,k] ----------------
// 128x128 tile, BK=32, 4 waves (2x2), 4x4 16x16x32 fragments per wave.
// 1D grid of 1024 blocks; XCD-chunked swizzle so each XCD owns 16 consecutive
// A row-panels (A fetched once per panel; whole B = 2MB fits each XCD L2).
#define BM 128
#define BN 128
#define BK 32

__device__ __forceinline__ void swz_block(int& br, int& bc) {
  int b  = blockIdx.x;                    // nwg = 1024, 8 XCDs, cpx = 128
  int wg = ((b & 7) << 7) | (b >> 3);     // (b%8)*128 + b/8  (bijective)
  br = wg >> 3;                           // 0..127
  bc = wg & 7;                            // 0..7
}

// f32-output variant (GEMM2)
__global__ __launch_bounds__(256) void gemm_bt(const ushort* __restrict__ A,
                                               const ushort* __restrict__ Bm,
                                               float* __restrict__ C,
                                               int M, int N, int K) {
  __shared__ ushort As[2][BM * BK];
  __shared__ ushort Bs[2][BN * BK];

  int tid  = threadIdx.x;
  int lane = tid & 63;
  int w    = tid >> 6;
  int wr   = w >> 1, wc = w & 1;
  int br, bc;
  swz_block(br, bc);

  const ushort* Abase = A  + (size_t)(br * BM) * K;
  const ushort* Bbase = Bm + (size_t)(bc * BN) * K;

  int srow = lane >> 2;
  int skk  = (lane & 3) * 8;

  f32x4 zero = {0.f, 0.f, 0.f, 0.f};
  f32x4 acc[4][4];
#pragma unroll
  for (int m = 0; m < 4; ++m)
#pragma unroll
    for (int n = 0; n < 4; ++n) acc[m][n] = zero;

  int NKT = K / BK;
  int cur = 0;

#pragma unroll
  for (int j = 0; j < 2; ++j) {
    int c = w * 2 + j;
    gload16(Abase + (size_t)(c * 16 + srow) * K + skk, &As[0][c * 512]);
    gload16(Bbase + (size_t)(c * 16 + srow) * K + skk, &Bs[0][c * 512]);
  }

  int fr = lane & 15;
  int fk = (lane >> 4) * 8;

  for (int kt = 0; kt < NKT; ++kt) {
    __syncthreads();
    if (kt + 1 < NKT) {
      int k0 = (kt + 1) * BK;
#pragma unroll
      for (int j = 0; j < 2; ++j) {
        int c = w * 2 + j;
        gload16(Abase + (size_t)(c * 16 + srow) * K + k0 + skk, &As[cur ^ 1][c * 512]);
        gload16(Bbase + (size_t)(c * 16 + srow) * K + k0 + skk, &Bs[cur ^ 1][c * 512]);
      }
    }
    bf16x8 af[4], bfr[4];
#pragma unroll
    for (int m = 0; m < 4; ++m)
      af[m] = *(const bf16x8*)&As[cur][(wr * 64 + m * 16 + fr) * BK + fk];
#pragma unroll
    for (int n = 0; n < 4; ++n)
      bfr[n] = *(const bf16x8*)&Bs[cur][(wc * 64 + n * 16 + fr) * BK + fk];
#pragma unroll
    for (int m = 0; m < 4; ++m)
#pragma unroll
      for (int n = 0; n < 4; ++n)
        acc[m][n] = __builtin_amdgcn_mfma_f32_16x16x32_bf16(af[m], bfr[n], acc[m][n], 0, 0, 0);
    cur ^= 1;
  }

  int row0 = br * BM + wr * 64 + (lane >> 4) * 4;
  int col0 = bc * BN + wc * 64 + (lane & 15);
#pragma unroll
  for (int m = 0; m < 4; ++m)
#pragma unroll
    for (int n = 0; n < 4; ++n)
#pragma unroll
      for (int i = 0; i < 4; ++i)
        C[(size_t)(row0 + m * 16 + i) * N + col0 + n * 16] = acc[m][n][i];
}

// bf16-output variant with fused quantum projection epilogue (GEMM1):
// qq[m,n] = cos(theta[n&63]) * cos(proj[m,n]), stored bf16.
__global__ __launch_bounds__(256) void gemm_bt_cos(const ushort* __restrict__ A,
                                                   const ushort* __restrict__ Bm,
                                                   ushort* __restrict__ Cq,
                                                   const float* __restrict__ theta,
                                                   int M, int N, int K) {
  __shared__ ushort As[2][BM * BK];
  __shared__ ushort Bs[2][BN * BK];

  int tid  = threadIdx.x;
  int lane = tid & 63;
  int w    = tid >> 6;
  int wr   = w >> 1, wc = w & 1;
  int br, bc;
  swz_block(br, bc);

  const ushort* Abase = A  + (size_t)(br * BM) * K;
  const ushort* Bbase = Bm + (size_t)(bc * BN) * K;

  int srow = lane >> 2;
  int skk  = (lane & 3) * 8;

  f32x4 zero = {0.f, 0.f, 0.f, 0.f};
  f32x4 acc[4][4];
#pragma unroll
  for (int m = 0; m < 4; ++m)
#pragma unroll
    for (int n = 0; n < 4; ++n) acc[m][n] = zero;

  int NKT = K / BK;
  int cur = 0;

#pragma unroll
  for (int j = 0; j < 2; ++j) {
    int c = w * 2 + j;
    gload16(Abase + (size_t)(c * 16 + srow) * K + skk, &As[0][c * 512]);
    gload16(Bbase + (size_t)(c * 16 + srow) * K + skk, &Bs[0][c * 512]);
  }

  int fr = lane & 15;
  int fk = (lane >> 4) * 8;

  for (int kt = 0; kt < NKT; ++kt) {
    __syncthreads();
    if (kt + 1 < NKT) {
      int k0 = (kt + 1) * BK;
#pragma unroll
      for (int j = 0; j < 2; ++j) {
        int c = w * 2 + j;
        gload16(Abase + (size_t)(c * 16 + srow) * K + k0 + skk, &As[cur ^ 1][c * 512]);
        gload16(Bbase + (size_t)(c * 16 + srow) * K + k0 + skk, &Bs[cur ^ 1][c * 512]);
      }
    }
    bf16x8 af[4], bfr[4];
#pragma unroll
    for (int m = 0; m < 4; ++m)
      af[m] = *(const bf16x8*)&As[cur][(wr * 64 + m * 16 + fr) * BK + fk];
#pragma unroll
    for (int n = 0; n < 4; ++n)
      bfr[n] = *(const bf16x8*)&Bs[cur][(wc * 64 + n * 16 + fr) * BK + fk];
#pragma unroll
    for (int m = 0; m < 4; ++m)
#pragma unroll
      for (int n = 0; n < 4; ++n)
        acc[m][n] = __builtin_amdgcn_mfma_f32_16x16x32_bf16(af[m], bfr[n], acc[m][n], 0, 0, 0);
    cur ^= 1;
  }

  // theta index for col = bc*128 + wc*64 + n*16 + fr is (n*16+fr) & 63 = n*16+fr
  float ct[4];
#pragma unroll
  for (int n = 0; n < 4; ++n) ct[n] = __cosf(theta[n * 16 + fr]);

  int row0 = br * BM + wr * 64 + (lane >> 4) * 4;
  int col0 = bc * BN + wc * 64 + fr;
#pragma unroll
  for (int m = 0; m < 4; ++m)
#pragma unroll
    for (int n = 0; n < 4; ++n)
#pragma unroll
      for (int i = 0; i < 4; ++i)
        Cq[(size_t)(row0 + m * 16 + i) * N + col0 + n * 16] =
            f2bf(ct[n] * __cosf(acc[m][n][i]));
}

// ---------------- per-token head-vs-head attention via MFMA ----------------
// 1 wave = 1 token. H[d][g] = qq[g*64+d] (g=head, d=wire).
// Scores: S = H^T H via self-product MFMA (frag serves as A and B).
// Softmax per column h (cross lane-group shfl reduce).
// PV: O^T[h][d] = sum_g P^T[h][g] * H^T[g][d]; A-frag = regrouped P (K padded
// to 32, lanes kb>=2 zeroed), B-frag = LDS-transposed H (swizzled, b128 reads).
__global__ __launch_bounds__(256) void attn_quantum(const ushort* __restrict__ qqb,
                                                    ushort* __restrict__ aout) {
  __shared__ ushort T[4][64 * 32];
  int tid = threadIdx.x;
  int wv  = tid >> 6, l = tid & 63;
  size_t tok = (size_t)blockIdx.x * 4 + wv;
  const ushort* src = qqb + tok * NE;
  ushort* Tw = T[wv];

  int h  = l & 15;   // head / fragment row-col index
  int kb = l >> 4;   // k-block 0..3

  bf16x8 f0 = *(const bf16x8*)(src + h * 64 + kb * 8);
  bf16x8 f1 = *(const bf16x8*)(src + h * 64 + kb * 8 + 32);

  // transpose into LDS (swizzled): T[d][h] = H[d][h]
#pragma unroll
  for (int jj = 0; jj < 8; ++jj) {
    int d0 = kb * 8 + jj;
    int d1 = d0 + 32;
    Tw[d0 * 32 + (((h >> 3) ^ ((d0 >> 3) & 3)) << 3) + (h & 7)] = (ushort)f0[jj];
    Tw[d1 * 32 + (((h >> 3) ^ ((d1 >> 3) & 3)) << 3) + (h & 7)] = (ushort)f1[jj];
  }

  // scores: S[i][j] = sum_d qq[i*64+d]*qq[j*64+d]; frag is both A and B
  f32x4 sa = {0.f, 0.f, 0.f, 0.f};
  sa = __builtin_amdgcn_mfma_f32_16x16x32_bf16(f0, f0, sa, 0, 0, 0);
  sa = __builtin_amdgcn_mfma_f32_16x16x32_bf16(f1, f1, sa, 0, 0, 0);

  float s[4];
#pragma unroll
  for (int i = 0; i < 4; ++i) s[i] = sa[i] * 0.125f;   // 1/sqrt(64)

  float mx = fmaxf(fmaxf(s[0], s[1]), fmaxf(s[2], s[3]));
  mx = fmaxf(mx, __shfl_xor(mx, 16));
  mx = fmaxf(mx, __shfl_xor(mx, 32));
  float e[4], sum = 0.f;
#pragma unroll
  for (int i = 0; i < 4; ++i) { e[i] = __expf(s[i] - mx); sum += e[i]; }
  sum += __shfl_xor(sum, 16);
  sum += __shfl_xor(sum, 32);
  float inv = 1.f / sum;
#pragma unroll
  for (int i = 0; i < 4; ++i) e[i] *= inv;   // P[g][h], normalized

  // regroup P into PV A-frag: lane (h,kb) needs P[kb*8+jj][h], jj=0..7
  int s1 = h + (kb & 1) * 32;
  float q1[4], q2[4];
#pragma unroll
  for (int i = 0; i < 4; ++i) {
    q1[i] = __shfl(e[i], s1);
    q2[i] = __shfl(e[i], s1 + 16);
  }
  bool live = (kb < 2);
  bf16x8 pa;
#pragma unroll
  for (int i = 0; i < 4; ++i) {
    pa[i]     = live ? (short)f2bf(q1[i]) : (short)0;
    pa[4 + i] = live ? (short)f2bf(q2[i]) : (short)0;
  }

  __syncthreads();  // LDS transpose visible

  f32x4 o[4];
#pragma unroll
  for (int c = 0; c < 4; ++c) {
    int r = c * 16 + h;
    int slot = (kb & 1) ^ ((r >> 3) & 3);
    bf16x8 bfrag = *(const bf16x8*)&Tw[r * 32 + slot * 8];
    f32x4 z = {0.f, 0.f, 0.f, 0.f};
    o[c] = __builtin_amdgcn_mfma_f32_16x16x32_bf16(pa, bfrag, z, 0, 0, 0);
  }

  ushort* dst = aout + tok * NE;
#pragma unroll
  for (int c = 0; c < 4; ++c)
#pragma unroll
    for (int i = 0; i < 4; ++i)
      dst[(kb * 4 + i) * NDK + c * 16 + h] = f2bf(o[c][i]);
}

// ---------------- launch ----------------
extern "C" void kernel_launch(void* const* d_in, const int* in_sizes, int n_in,
                              void* d_out, int out_size, void* d_ws, size_t ws_size,
                              hipStream_t stream) {
  const float* x     = (const float*)d_in[0];
  const float* W     = (const float*)d_in[1];
  const float* theta = (const float*)d_in[2];
  float* out = (float*)d_out;

  char* ws = (char*)d_ws;
  ushort* xb  = (ushort*)ws;                                   // 32 MB
  ushort* Wb  = (ushort*)(ws + (size_t)MTOK * NE * 2);         // 2 MB
  ushort* qqb = (ushort*)(ws + (size_t)MTOK * NE * 2 + (size_t)NE * NE * 2); // 32 MB
  ushort* aout = xb;  // reuse: xb dead after GEMM1

  cvt_bf16<<<1024, 256, 0, stream>>>(x, xb, MTOK * NE / 4);
  cvt_bf16<<<256, 256, 0, stream>>>(W, Wb, NE * NE / 4);

  int nwg = (NE / BN) * (MTOK / BM);  // 8 * 128 = 1024, divisible by 8
  gemm_bt_cos<<<nwg, 256, 0, stream>>>(xb, Wb, qqb, theta, MTOK, NE, NE);

  attn_quantum<<<MTOK / 4, 256, 0, stream>>>(qqb, aout);

  gemm_bt<<<nwg, 256, 0, stream>>>(aout, Wb, out, MTOK, NE, NE);
}